// Round 11
// baseline (225.072 us; speedup 1.0000x reference)
//
#include <hip/hip_runtime.h>
#include <hip/hip_bf16.h>
#include <stdint.h>

#define DI __device__ __forceinline__

typedef __bf16 bf16x8 __attribute__((ext_vector_type(8)));
typedef float f32x4 __attribute__((ext_vector_type(4)));
typedef unsigned short u16;

// ---------- helpers ----------
DI u16 f2bf(float f) {
  union { float f; uint32_t u; } x; x.f = f;
  uint32_t r = (x.u + 0x7FFFu + ((x.u >> 16) & 1u)) >> 16;
  return (u16)r;
}
DI bf16x8 load16(const u16* p) { return *(const bf16x8*)p; }

DI void async_copy16(void* lds, const void* g) {
  __builtin_amdgcn_global_load_lds(
      (const __attribute__((address_space(1))) uint32_t*)g,
      (__attribute__((address_space(3))) uint32_t*)lds, 16, 0, 0);
}

DI f32x4 mfma16(bf16x8 a, bf16x8 b, f32x4 c) {
  return __builtin_amdgcn_mfma_f32_16x16x32_bf16(a, b, c, 0, 0, 0);
}

// pack 2 floats -> 2 bf16 (one v_cvt_pk_bf16_f32); low 16 bits = a
DI uint32_t pk_bf16(float a, float b) {
  union { __hip_bfloat162 v; uint32_t u; } r;
  r.v = __float22bfloat162_rn(make_float2(a, b));
  return r.u;
}

// scale * log2(e), folded into Q at GEMM1 epilogue
#define QSCALE (0.125f * 1.44269504088896340736f)

// ---------- fused fp32 -> bf16 conversion of all three inputs ----------
__global__ __launch_bounds__(256)
void cvt_all(const float* __restrict__ s0, u16* __restrict__ d0, int n0,
             const float* __restrict__ s1, u16* __restrict__ d1, int n1,
             const float* __restrict__ s2, u16* __restrict__ d2, int n2) {
  int i = (blockIdx.x * 256 + threadIdx.x) * 4;
  const float* s; u16* d;
  if (i < n0) { s = s0 + i; d = d0 + i; }
  else if (i < n0 + n1) { s = s1 + (i - n0); d = d1 + (i - n0); }
  else if (i < n0 + n1 + n2) { s = s2 + (i - n0 - n1); d = d2 + (i - n0 - n1); }
  else return;
  float4 v = *(const float4*)s;
  ushort4 o;
  o.x = f2bf(v.x); o.y = f2bf(v.y); o.z = f2bf(v.z); o.w = f2bf(v.w);
  *(ushort4*)d = o;
}

// ---------- QKV GEMM: 256x128 tile, 512 thr / 8 waves, BK=32, dbuf ----------
// r10 lesson: 2-phase loop is drain-bound -> raise FLOP per staged byte.
// 256x128: 87 FLOP/B staged (vs 64 at 128^2); 24 iters cover 2x FLOPs/block
// -> half the barrier drains per FLOP. Wave tile 128x32 (2m x 4n), acc[8][2].
// LDS 2x(16+8) = 48 KB; ~130 VGPR -> 2 blocks/CU = 16 waves (same as r10).
__global__ __launch_bounds__(512)
void gemm_qkv(const u16* __restrict__ A, const u16* __restrict__ Bm,
              u16* __restrict__ Qb, u16* __restrict__ Kb, u16* __restrict__ Vt,
              int M, int N, int K) {
  __shared__ u16 As[2][256 * 32];
  __shared__ u16 Bs[2][128 * 32];

  const int tid  = threadIdx.x;
  const int lane = tid & 63;
  const int wave = tid >> 6;
  // T1 XCD-aware swizzle: 576 blocks = 8 xcd x 72
  const int lb  = blockIdx.x + 18 * blockIdx.y;
  const int swz = (lb & 7) * 72 + (lb >> 3);
  const int n0 = (swz % 18) * 128;
  const int m0 = (swz / 18) * 256;
  const int wm = (wave & 1) * 128;
  const int wn = (wave >> 1) * 32;
  const int c = lane & 15;
  const int g = lane >> 4;

  f32x4 acc[8][2] = {};

  // prologue: stage k0=0 into buf 0 (A: 2 chunks/thread, B: 1)
#pragma unroll
  for (int i = 0; i < 2; ++i) {
    int j = i * 512 + tid;
    int row = j >> 2, col = (j & 3) * 8;
    async_copy16(&As[0][j * 8], &A[(size_t)(m0 + row) * K + col]);
  }
  {
    int row = tid >> 2, col = (tid & 3) * 8;
    async_copy16(&Bs[0][tid * 8], &Bm[(size_t)(n0 + row) * K + col]);
  }

  int cur = 0;
  for (int k0 = 0; k0 < K; k0 += 32) {
    __syncthreads();                 // buf[cur] ready (staged an iter ago)

    if (k0 + 32 < K) {               // issue next-tile stage into other buffer
#pragma unroll
      for (int i = 0; i < 2; ++i) {
        int j = i * 512 + tid;
        int row = j >> 2, col = (j & 3) * 8;
        async_copy16(&As[cur ^ 1][j * 8],
                     &A[(size_t)(m0 + row) * K + k0 + 32 + col]);
      }
      {
        int row = tid >> 2, col = (tid & 3) * 8;
        async_copy16(&Bs[cur ^ 1][tid * 8],
                     &Bm[(size_t)(n0 + row) * K + k0 + 32 + col]);
      }
    }

    bf16x8 af[8], bfr[2];
#pragma unroll
    for (int t = 0; t < 8; ++t)
      af[t] = *(const bf16x8*)&As[cur][(wm + t * 16 + c) * 32 + g * 8];
#pragma unroll
    for (int t = 0; t < 2; ++t)
      bfr[t] = *(const bf16x8*)&Bs[cur][(wn + t * 16 + c) * 32 + g * 8];
#pragma unroll
    for (int mt = 0; mt < 8; ++mt)
#pragma unroll
      for (int nt = 0; nt < 2; ++nt)
        acc[mt][nt] = mfma16(af[mt], bfr[nt], acc[mt][nt]);
    cur ^= 1;
  }

  if (n0 < 768) {            // Q, pre-scaled
#pragma unroll
    for (int nt = 0; nt < 2; ++nt) {
      int col = n0 + wn + nt * 16 + c;
#pragma unroll
      for (int mt = 0; mt < 8; ++mt)
#pragma unroll
        for (int r = 0; r < 4; ++r) {
          int row = m0 + wm + mt * 16 + g * 4 + r;
          Qb[(size_t)row * 768 + col] = f2bf(acc[mt][nt][r] * QSCALE);
        }
    }
  } else if (n0 < 1536) {    // K
#pragma unroll
    for (int nt = 0; nt < 2; ++nt) {
      int col = n0 - 768 + wn + nt * 16 + c;
#pragma unroll
      for (int mt = 0; mt < 8; ++mt)
#pragma unroll
        for (int r = 0; r < 4; ++r) {
          int row = m0 + wm + mt * 16 + g * 4 + r;
          Kb[(size_t)row * 768 + col] = f2bf(acc[mt][nt][r]);
        }
    }
  } else {                   // V transposed: Vt[((b*12+h)*64+d)*2048 + nseq]
#pragma unroll
    for (int nt = 0; nt < 2; ++nt) {
      int cv = n0 - 1536 + wn + nt * 16 + c;
      int hv = cv >> 6, d = cv & 63;
#pragma unroll
      for (int mt = 0; mt < 8; ++mt) {
        int row = m0 + wm + mt * 16 + g * 4;  // 4 consecutive rows
        int b = row >> 11, nn = row & 2047;
        ushort4 o;
        o.x = f2bf(acc[mt][nt][0]); o.y = f2bf(acc[mt][nt][1]);
        o.z = f2bf(acc[mt][nt][2]); o.w = f2bf(acc[mt][nt][3]);
        *(ushort4*)&Vt[(((size_t)b * 12 + hv) * 64 + d) * 2048 + nn] = o;
      }
    }
  }
}

// ---------- GEMM2: 128x64 tile (grid 768 = 3/CU), BK=32, dbuf (r10) ----------
__global__ __launch_bounds__(256)
void gemm_proj(const u16* __restrict__ A, const u16* __restrict__ Bm,
               const float* __restrict__ bias, float* __restrict__ Co,
               int M, int N, int K) {
  __shared__ u16 As[2][128 * 32];
  __shared__ u16 Bs[2][64 * 32];

  const int tid  = threadIdx.x;
  const int lane = tid & 63;
  const int wave = tid >> 6;
  // T1 XCD-aware swizzle: 768 blocks = 8 xcd x 96
  const int lb  = blockIdx.x + 12 * blockIdx.y;
  const int swz = (lb & 7) * 96 + (lb >> 3);
  const int n0 = (swz % 12) * 64;
  const int m0 = (swz / 12) * 128;
  const int wm = (wave & 1) * 64;
  const int wn = (wave >> 1) * 32;
  const int c = lane & 15;
  const int g = lane >> 4;

  f32x4 acc[4][2] = {};

#pragma unroll
  for (int i = 0; i < 2; ++i) {
    int j = i * 256 + tid;
    int row = j >> 2, col = (j & 3) * 8;
    async_copy16(&As[0][j * 8], &A[(size_t)(m0 + row) * K + col]);
  }
  {
    int row = tid >> 2, col = (tid & 3) * 8;
    async_copy16(&Bs[0][tid * 8], &Bm[(size_t)(n0 + row) * K + col]);
  }

  int cur = 0;
  for (int k0 = 0; k0 < K; k0 += 32) {
    __syncthreads();

    if (k0 + 32 < K) {
#pragma unroll
      for (int i = 0; i < 2; ++i) {
        int j = i * 256 + tid;
        int row = j >> 2, col = (j & 3) * 8;
        async_copy16(&As[cur ^ 1][j * 8],
                     &A[(size_t)(m0 + row) * K + k0 + 32 + col]);
      }
      {
        int row = tid >> 2, col = (tid & 3) * 8;
        async_copy16(&Bs[cur ^ 1][tid * 8],
                     &Bm[(size_t)(n0 + row) * K + k0 + 32 + col]);
      }
    }

    bf16x8 af[4], bfr[2];
#pragma unroll
    for (int t = 0; t < 4; ++t)
      af[t] = *(const bf16x8*)&As[cur][(wm + t * 16 + c) * 32 + g * 8];
#pragma unroll
    for (int t = 0; t < 2; ++t)
      bfr[t] = *(const bf16x8*)&Bs[cur][(wn + t * 16 + c) * 32 + g * 8];
#pragma unroll
    for (int mt = 0; mt < 4; ++mt)
#pragma unroll
      for (int nt = 0; nt < 2; ++nt)
        acc[mt][nt] = mfma16(af[mt], bfr[nt], acc[mt][nt]);
    cur ^= 1;
  }

#pragma unroll
  for (int nt = 0; nt < 2; ++nt) {
    int col = n0 + wn + nt * 16 + c;
    float bv = bias[col];
#pragma unroll
    for (int mt = 0; mt < 4; ++mt)
#pragma unroll
      for (int r = 0; r < 4; ++r) {
        int row = m0 + wm + mt * 16 + g * 4 + r;
        Co[(size_t)row * N + col] = acc[mt][nt][r] + bv;
      }
  }
}

// ---------- Flash attention v5 + XCD swizzle (datapath UNCHANGED) ----------
// v5 = measured-best 80 us. Added ONLY the T1 block swizzle (exact mapping
// that passed numerics in v10/v11): groups the 16 q-chunk blocks of each
// (b,h) panel onto one XCD -> K/V staging served from L2 (~200cyc) instead
// of HBM (~900cyc); FETCH 104.5 -> ~18.5 MB (measured r3/r6).
__global__ __launch_bounds__(256)
void attn_flash(const u16* __restrict__ Qb, const u16* __restrict__ Kb,
                const u16* __restrict__ Vt, u16* __restrict__ out) {
  __shared__ u16 Ks[2][2 * 64 * 32];
  __shared__ u16 Vs[2][2 * 64 * 32];
  __shared__ __align__(16) u16 Plds[4][32 * 72];  // 32q x 64k, stride 72

  const int tid  = threadIdx.x;
  const int lane = tid & 63;
  const int wave = tid >> 6;
  // T1 XCD swizzle: 768 blocks = 8 xcd x 96
  const int bid = blockIdx.x;
  const int swz = (bid & 7) * 96 + (bid >> 3);
  const int qchunk = swz & 15;        // N/128 = 16
  const int h = (swz >> 4) % 12;
  const int b = swz / 192;
  const int q0 = qchunk * 128 + wave * 32;
  const int c = lane & 15;
  const int g = lane >> 4;

  const u16* Qp = Qb + (size_t)b * 2048 * 768 + h * 64;   // row stride 768
  const u16* Kp = Kb + (size_t)b * 2048 * 768 + h * 64;
  const u16* Vp = Vt + ((size_t)b * 12 + h) * 64 * 2048;  // [d][nseq]

  u16* pw = &Plds[wave][0];

  // two q sub-tiles of 16 rows, two d-halves each (B-operand fragments)
  const bf16x8 qf0 = load16(&Qp[(size_t)(q0 + c) * 768 + g * 8]);
  const bf16x8 qf1 = load16(&Qp[(size_t)(q0 + c) * 768 + 32 + g * 8]);
  const bf16x8 qg0 = load16(&Qp[(size_t)(q0 + 16 + c) * 768 + g * 8]);
  const bf16x8 qg1 = load16(&Qp[(size_t)(q0 + 16 + c) * 768 + 32 + g * 8]);

  const int kk = tid >> 2;          // staged row 0..63
  const int ch = (tid & 3) * 8;     // u16 chunk offset within 32

  float lsum0 = 0.f, lsum1 = 0.f;
  f32x4 o0[4] = {}, o1[4] = {};

  // prologue: stage step 0 into buf 0
  async_copy16(&Ks[0][tid * 8],        &Kp[(size_t)kk * 768 + ch]);
  async_copy16(&Ks[0][2048 + tid * 8], &Kp[(size_t)kk * 768 + 32 + ch]);
  async_copy16(&Vs[0][tid * 8],        &Vp[(size_t)kk * 2048 + ch]);
  async_copy16(&Vs[0][2048 + tid * 8], &Vp[(size_t)kk * 2048 + 32 + ch]);

  int cur = 0;
  for (int k0 = 0; k0 < 2048; k0 += 64) {
    __syncthreads();  // drains this step's stage; protects buf^1 overwrite

    if (k0 + 64 < 2048) {             // stage next step into the other buffer
      int nxt = cur ^ 1, kn = k0 + 64;
      async_copy16(&Ks[nxt][tid * 8],        &Kp[(size_t)(kn + kk) * 768 + ch]);
      async_copy16(&Ks[nxt][2048 + tid * 8], &Kp[(size_t)(kn + kk) * 768 + 32 + ch]);
      async_copy16(&Vs[nxt][tid * 8],        &Vp[(size_t)kk * 2048 + kn + ch]);
      async_copy16(&Vs[nxt][2048 + tid * 8], &Vp[(size_t)kk * 2048 + kn + 32 + ch]);
    }

    // ---- QK^T swapped: s[kt][r] = P[q=c][k = kt*16 + g*4 + r] ----
    f32x4 s0[4] = {}, s1[4] = {};
#pragma unroll
    for (int kt = 0; kt < 4; ++kt) {
      bf16x8 kf0 = *(const bf16x8*)&Ks[cur][(kt * 16 + c) * 32 + g * 8];
      bf16x8 kf1 = *(const bf16x8*)&Ks[cur][2048 + (kt * 16 + c) * 32 + g * 8];
      s0[kt] = mfma16(kf0, qf0, s0[kt]);
      s0[kt] = mfma16(kf1, qf1, s0[kt]);
      s1[kt] = mfma16(kf0, qg0, s1[kt]);
      s1[kt] = mfma16(kf1, qg1, s1[kt]);
    }

    // ---- P = exp2(S): k-contiguous per lane -> one b64 write per (kt,sub) ----
#pragma unroll
    for (int kt = 0; kt < 4; ++kt) {
      float p0 = __builtin_amdgcn_exp2f(s0[kt][0]);
      float p1 = __builtin_amdgcn_exp2f(s0[kt][1]);
      float p2 = __builtin_amdgcn_exp2f(s0[kt][2]);
      float p3 = __builtin_amdgcn_exp2f(s0[kt][3]);
      lsum0 += (p0 + p1) + (p2 + p3);
      uint2 w; w.x = pk_bf16(p0, p1); w.y = pk_bf16(p2, p3);
      *(uint2*)&pw[c * 72 + kt * 16 + g * 4] = w;

      float r0 = __builtin_amdgcn_exp2f(s1[kt][0]);
      float r1 = __builtin_amdgcn_exp2f(s1[kt][1]);
      float r2 = __builtin_amdgcn_exp2f(s1[kt][2]);
      float r3 = __builtin_amdgcn_exp2f(s1[kt][3]);
      lsum1 += (r0 + r1) + (r2 + r3);
      uint2 w2; w2.x = pk_bf16(r0, r1); w2.y = pk_bf16(r2, r3);
      *(uint2*)&pw[(16 + c) * 72 + kt * 16 + g * 4] = w2;
    }
    __asm__ volatile("s_waitcnt lgkmcnt(0)" ::: "memory");

    // ---- PV: P A-frags (b128 pattern), V B-frags shared ----
#pragma unroll
    for (int kt2 = 0; kt2 < 2; ++kt2) {
      const bf16x8 pf0 = *(const bf16x8*)&pw[c * 72 + kt2 * 32 + g * 8];
      const bf16x8 pf1 = *(const bf16x8*)&pw[(16 + c) * 72 + kt2 * 32 + g * 8];
#pragma unroll
      for (int dt = 0; dt < 4; ++dt) {
        bf16x8 vf = *(const bf16x8*)&Vs[cur][kt2 * 2048 + (dt * 16 + c) * 32 + g * 8];
        o0[dt] = mfma16(pf0, vf, o0[dt]);
        o1[dt] = mfma16(pf1, vf, o1[dt]);
      }
    }
    cur ^= 1;
  }

  // row sums: lane (c,g) holds the g-slice of row q=c; reduce over g, then
  // broadcast to the C/D row layout (row = g*4 + r).
  float t0 = lsum0 + __shfl_xor(lsum0, 16);
  t0 += __shfl_xor(t0, 32);
  float t1 = lsum1 + __shfl_xor(lsum1, 16);
  t1 += __shfl_xor(t1, 32);
  float inv0 = 1.f / t0;
  float inv1 = 1.f / t1;
  float invr0[4], invr1[4];
#pragma unroll
  for (int r = 0; r < 4; ++r) {
    invr0[r] = __shfl(inv0, g * 4 + r);   // source lane q = g*4+r (lane < 16)
    invr1[r] = __shfl(inv1, g * 4 + r);
  }

#pragma unroll
  for (int dt = 0; dt < 4; ++dt)
#pragma unroll
    for (int r = 0; r < 4; ++r) {
      int n = q0 + g * 4 + r;
      out[(size_t)(b * 2048 + n) * 768 + h * 64 + dt * 16 + c] =
          f2bf(o0[dt][r] * invr0[r]);
      out[(size_t)(b * 2048 + n + 16) * 768 + h * 64 + dt * 16 + c] =
          f2bf(o1[dt][r] * invr1[r]);
    }
}

// ---------- launcher ----------
extern "C" void kernel_launch(void* const* d_in, const int* in_sizes, int n_in,
                              void* d_out, int out_size, void* d_ws, size_t ws_size,
                              hipStream_t stream) {
  const float* x      = (const float*)d_in[0];  // [4,2048,768] fp32
  const float* w_qkv  = (const float*)d_in[1];  // [2304,768]
  const float* w_proj = (const float*)d_in[2];  // [768,768]
  const float* b_proj = (const float*)d_in[3];  // [768]
  float* out = (float*)d_out;                   // [4,2048,768] fp32

  const int M = 8192;     // B*N
  const int C = 768;
  const int NQKV = 2304;

  // workspace layout (bf16 elements) — total ~33.8M u16 = 67.7 MB
  u16* xb     = (u16*)d_ws;                        // 8192*768
  u16* wqkvb  = xb + (size_t)M * C;                // 2304*768
  u16* wprojb = wqkvb + (size_t)NQKV * C;          // 768*768
  u16* Qb     = wprojb + (size_t)C * C;            // 8192*768
  u16* Kb     = Qb + (size_t)M * C;                // 8192*768
  u16* Vt     = Kb + (size_t)M * C;                // 4*12*64*2048
  u16* attn   = Vt + (size_t)M * C;                // 8192*768

  dim3 blk(256);
  // 0) convert all fp32 inputs to bf16 in one launch
  const int n0 = M * C, n1 = NQKV * C, n2 = C * C;
  cvt_all<<<dim3((n0 + n1 + n2) / 1024), blk, 0, stream>>>(
      x, xb, n0, w_qkv, wqkvb, n1, w_proj, wprojb, n2);

  // 1) qkv GEMM (256x128 tile, 512 threads, dbuf)
  gemm_qkv<<<dim3(NQKV / 128, M / 256), dim3(512), 0, stream>>>(
      xb, wqkvb, Qb, Kb, Vt, M, NQKV, C);
  // 2) flash attention (v5 + XCD swizzle)
  attn_flash<<<dim3(4 * 12 * 16), blk, 0, stream>>>(Qb, Kb, Vt, attn);
  // 3) out = attn @ w_proj^T + b  (fp32 out, 128x64 tile, dbuf)
  gemm_proj<<<dim3(C / 64, M / 128), blk, 0, stream>>>(
      attn, wprojb, b_proj, out, M, C, C);
}

// Round 12
// 224.113 us; speedup vs baseline: 1.0043x; 1.0043x over previous
//
#include <hip/hip_runtime.h>
#include <hip/hip_bf16.h>
#include <stdint.h>

#define DI __device__ __forceinline__

typedef __bf16 bf16x8 __attribute__((ext_vector_type(8)));
typedef float f32x4 __attribute__((ext_vector_type(4)));
typedef unsigned short u16;

// ---------- helpers ----------
DI u16 f2bf(float f) {
  union { float f; uint32_t u; } x; x.f = f;
  uint32_t r = (x.u + 0x7FFFu + ((x.u >> 16) & 1u)) >> 16;
  return (u16)r;
}
DI bf16x8 load16(const u16* p) { return *(const bf16x8*)p; }

DI void async_copy16(void* lds, const void* g) {
  __builtin_amdgcn_global_load_lds(
      (const __attribute__((address_space(1))) uint32_t*)g,
      (__attribute__((address_space(3))) uint32_t*)lds, 16, 0, 0);
}

DI f32x4 mfma16(bf16x8 a, bf16x8 b, f32x4 c) {
  return __builtin_amdgcn_mfma_f32_16x16x32_bf16(a, b, c, 0, 0, 0);
}

// pack 2 floats -> 2 bf16 (one v_cvt_pk_bf16_f32); low 16 bits = a
DI uint32_t pk_bf16(float a, float b) {
  union { __hip_bfloat162 v; uint32_t u; } r;
  r.v = __float22bfloat162_rn(make_float2(a, b));
  return r.u;
}

// scale * log2(e), folded into Q at GEMM1 epilogue
#define QSCALE (0.125f * 1.44269504088896340736f)

// ---------- fused fp32 -> bf16 conversion of all three inputs ----------
__global__ __launch_bounds__(256)
void cvt_all(const float* __restrict__ s0, u16* __restrict__ d0, int n0,
             const float* __restrict__ s1, u16* __restrict__ d1, int n1,
             const float* __restrict__ s2, u16* __restrict__ d2, int n2) {
  int i = (blockIdx.x * 256 + threadIdx.x) * 4;
  const float* s; u16* d;
  if (i < n0) { s = s0 + i; d = d0 + i; }
  else if (i < n0 + n1) { s = s1 + (i - n0); d = d1 + (i - n0); }
  else if (i < n0 + n1 + n2) { s = s2 + (i - n0 - n1); d = d2 + (i - n0 - n1); }
  else return;
  float4 v = *(const float4*)s;
  ushort4 o;
  o.x = f2bf(v.x); o.y = f2bf(v.y); o.z = f2bf(v.z); o.w = f2bf(v.w);
  *(ushort4*)d = o;
}

// ---------- QKV GEMM: 128^2 tile, BK=32, dbuf, ONE barrier/iter (r10-best) ----------
// r11 lesson: 256x128/512thr regressed (+7.4 us: 2.25 blocks/CU imbalance,
// longer per-wave chain at ~4 waves/SIMD). This exact version measured best
// in r10 (total 221.2).
__global__ __launch_bounds__(256)
void gemm_qkv(const u16* __restrict__ A, const u16* __restrict__ Bm,
              u16* __restrict__ Qb, u16* __restrict__ Kb, u16* __restrict__ Vt,
              int M, int N, int K) {
  __shared__ u16 As[2][128 * 32];
  __shared__ u16 Bs[2][128 * 32];

  const int tid  = threadIdx.x;
  const int lane = tid & 63;
  const int wave = tid >> 6;
  // T1 XCD-aware swizzle: 1152 blocks = 8 xcd x 144
  const int lb  = blockIdx.x + 18 * blockIdx.y;
  const int swz = (lb & 7) * 144 + (lb >> 3);
  const int n0 = (swz % 18) * 128;
  const int m0 = (swz / 18) * 128;
  const int wm = (wave & 1) * 64;
  const int wn = (wave >> 1) * 64;
  const int c = lane & 15;
  const int g = lane >> 4;

  f32x4 acc[4][4] = {};

  // prologue: stage k0=0 into buf 0
#pragma unroll
  for (int i = 0; i < 2; ++i) {
    int j = i * 256 + tid;
    int row = j >> 2;
    int col = (j & 3) * 8;
    async_copy16(&As[0][j * 8], &A[(size_t)(m0 + row) * K + col]);
    async_copy16(&Bs[0][j * 8], &Bm[(size_t)(n0 + row) * K + col]);
  }

  int cur = 0;
  for (int k0 = 0; k0 < K; k0 += 32) {
    __syncthreads();                 // buf[cur] ready (staged an iter ago)

    if (k0 + 32 < K) {               // issue next-tile stage into other buffer
#pragma unroll
      for (int i = 0; i < 2; ++i) {
        int j = i * 256 + tid;
        int row = j >> 2;
        int col = (j & 3) * 8;
        async_copy16(&As[cur ^ 1][j * 8],
                     &A[(size_t)(m0 + row) * K + k0 + 32 + col]);
        async_copy16(&Bs[cur ^ 1][j * 8],
                     &Bm[(size_t)(n0 + row) * K + k0 + 32 + col]);
      }
    }

    bf16x8 af[4], bfr[4];
#pragma unroll
    for (int t = 0; t < 4; ++t) {
      af[t]  = *(const bf16x8*)&As[cur][(wm + t * 16 + c) * 32 + g * 8];
      bfr[t] = *(const bf16x8*)&Bs[cur][(wn + t * 16 + c) * 32 + g * 8];
    }
#pragma unroll
    for (int mt = 0; mt < 4; ++mt)
#pragma unroll
      for (int nt = 0; nt < 4; ++nt)
        acc[mt][nt] = mfma16(af[mt], bfr[nt], acc[mt][nt]);
    cur ^= 1;
  }

  if (n0 < 768) {            // Q, pre-scaled
#pragma unroll
    for (int nt = 0; nt < 4; ++nt) {
      int col = n0 + wn + nt * 16 + c;
#pragma unroll
      for (int mt = 0; mt < 4; ++mt)
#pragma unroll
        for (int r = 0; r < 4; ++r) {
          int row = m0 + wm + mt * 16 + g * 4 + r;
          Qb[(size_t)row * 768 + col] = f2bf(acc[mt][nt][r] * QSCALE);
        }
    }
  } else if (n0 < 1536) {    // K
#pragma unroll
    for (int nt = 0; nt < 4; ++nt) {
      int col = n0 - 768 + wn + nt * 16 + c;
#pragma unroll
      for (int mt = 0; mt < 4; ++mt)
#pragma unroll
        for (int r = 0; r < 4; ++r) {
          int row = m0 + wm + mt * 16 + g * 4 + r;
          Kb[(size_t)row * 768 + col] = f2bf(acc[mt][nt][r]);
        }
    }
  } else {                   // V transposed: Vt[((b*12+h)*64+d)*2048 + nseq]
#pragma unroll
    for (int nt = 0; nt < 4; ++nt) {
      int cv = n0 - 1536 + wn + nt * 16 + c;
      int hv = cv >> 6, d = cv & 63;
#pragma unroll
      for (int mt = 0; mt < 4; ++mt) {
        int row = m0 + wm + mt * 16 + g * 4;  // 4 consecutive rows
        int b = row >> 11, nn = row & 2047;
        ushort4 o;
        o.x = f2bf(acc[mt][nt][0]); o.y = f2bf(acc[mt][nt][1]);
        o.z = f2bf(acc[mt][nt][2]); o.w = f2bf(acc[mt][nt][3]);
        *(ushort4*)&Vt[(((size_t)b * 12 + hv) * 64 + d) * 2048 + nn] = o;
      }
    }
  }
}

// ---------- GEMM2: 128x64 tile (grid 768 = 3/CU), BK=32, dbuf (r10-best) ----------
__global__ __launch_bounds__(256)
void gemm_proj(const u16* __restrict__ A, const u16* __restrict__ Bm,
               const float* __restrict__ bias, float* __restrict__ Co,
               int M, int N, int K) {
  __shared__ u16 As[2][128 * 32];
  __shared__ u16 Bs[2][64 * 32];

  const int tid  = threadIdx.x;
  const int lane = tid & 63;
  const int wave = tid >> 6;
  // T1 XCD-aware swizzle: 768 blocks = 8 xcd x 96
  const int lb  = blockIdx.x + 12 * blockIdx.y;
  const int swz = (lb & 7) * 96 + (lb >> 3);
  const int n0 = (swz % 12) * 64;
  const int m0 = (swz / 12) * 128;
  const int wm = (wave & 1) * 64;
  const int wn = (wave >> 1) * 32;
  const int c = lane & 15;
  const int g = lane >> 4;

  f32x4 acc[4][2] = {};

#pragma unroll
  for (int i = 0; i < 2; ++i) {
    int j = i * 256 + tid;
    int row = j >> 2, col = (j & 3) * 8;
    async_copy16(&As[0][j * 8], &A[(size_t)(m0 + row) * K + col]);
  }
  {
    int row = tid >> 2, col = (tid & 3) * 8;
    async_copy16(&Bs[0][tid * 8], &Bm[(size_t)(n0 + row) * K + col]);
  }

  int cur = 0;
  for (int k0 = 0; k0 < K; k0 += 32) {
    __syncthreads();

    if (k0 + 32 < K) {
#pragma unroll
      for (int i = 0; i < 2; ++i) {
        int j = i * 256 + tid;
        int row = j >> 2, col = (j & 3) * 8;
        async_copy16(&As[cur ^ 1][j * 8],
                     &A[(size_t)(m0 + row) * K + k0 + 32 + col]);
      }
      {
        int row = tid >> 2, col = (tid & 3) * 8;
        async_copy16(&Bs[cur ^ 1][tid * 8],
                     &Bm[(size_t)(n0 + row) * K + k0 + 32 + col]);
      }
    }

    bf16x8 af[4], bfr[2];
#pragma unroll
    for (int t = 0; t < 4; ++t)
      af[t] = *(const bf16x8*)&As[cur][(wm + t * 16 + c) * 32 + g * 8];
#pragma unroll
    for (int t = 0; t < 2; ++t)
      bfr[t] = *(const bf16x8*)&Bs[cur][(wn + t * 16 + c) * 32 + g * 8];
#pragma unroll
    for (int mt = 0; mt < 4; ++mt)
#pragma unroll
      for (int nt = 0; nt < 2; ++nt)
        acc[mt][nt] = mfma16(af[mt], bfr[nt], acc[mt][nt]);
    cur ^= 1;
  }

#pragma unroll
  for (int nt = 0; nt < 2; ++nt) {
    int col = n0 + wn + nt * 16 + c;
    float bv = bias[col];
#pragma unroll
    for (int mt = 0; mt < 4; ++mt)
#pragma unroll
      for (int r = 0; r < 4; ++r) {
        int row = m0 + wm + mt * 16 + g * 4 + r;
        Co[(size_t)row * N + col] = acc[mt][nt][r] + bv;
      }
  }
}

// ---------- Flash attention v5 + XCD swizzle (r11-best: 78.0 us) ----------
__global__ __launch_bounds__(256)
void attn_flash(const u16* __restrict__ Qb, const u16* __restrict__ Kb,
                const u16* __restrict__ Vt, u16* __restrict__ out) {
  __shared__ u16 Ks[2][2 * 64 * 32];
  __shared__ u16 Vs[2][2 * 64 * 32];
  __shared__ __align__(16) u16 Plds[4][32 * 72];  // 32q x 64k, stride 72

  const int tid  = threadIdx.x;
  const int lane = tid & 63;
  const int wave = tid >> 6;
  // T1 XCD swizzle: 768 blocks = 8 xcd x 96
  const int bid = blockIdx.x;
  const int swz = (bid & 7) * 96 + (bid >> 3);
  const int qchunk = swz & 15;        // N/128 = 16
  const int h = (swz >> 4) % 12;
  const int b = swz / 192;
  const int q0 = qchunk * 128 + wave * 32;
  const int c = lane & 15;
  const int g = lane >> 4;

  const u16* Qp = Qb + (size_t)b * 2048 * 768 + h * 64;   // row stride 768
  const u16* Kp = Kb + (size_t)b * 2048 * 768 + h * 64;
  const u16* Vp = Vt + ((size_t)b * 12 + h) * 64 * 2048;  // [d][nseq]

  u16* pw = &Plds[wave][0];

  // two q sub-tiles of 16 rows, two d-halves each (B-operand fragments)
  const bf16x8 qf0 = load16(&Qp[(size_t)(q0 + c) * 768 + g * 8]);
  const bf16x8 qf1 = load16(&Qp[(size_t)(q0 + c) * 768 + 32 + g * 8]);
  const bf16x8 qg0 = load16(&Qp[(size_t)(q0 + 16 + c) * 768 + g * 8]);
  const bf16x8 qg1 = load16(&Qp[(size_t)(q0 + 16 + c) * 768 + 32 + g * 8]);

  const int kk = tid >> 2;          // staged row 0..63
  const int ch = (tid & 3) * 8;     // u16 chunk offset within 32

  float lsum0 = 0.f, lsum1 = 0.f;
  f32x4 o0[4] = {}, o1[4] = {};

  // prologue: stage step 0 into buf 0
  async_copy16(&Ks[0][tid * 8],        &Kp[(size_t)kk * 768 + ch]);
  async_copy16(&Ks[0][2048 + tid * 8], &Kp[(size_t)kk * 768 + 32 + ch]);
  async_copy16(&Vs[0][tid * 8],        &Vp[(size_t)kk * 2048 + ch]);
  async_copy16(&Vs[0][2048 + tid * 8], &Vp[(size_t)kk * 2048 + 32 + ch]);

  int cur = 0;
  for (int k0 = 0; k0 < 2048; k0 += 64) {
    __syncthreads();  // drains this step's stage; protects buf^1 overwrite

    if (k0 + 64 < 2048) {             // stage next step into the other buffer
      int nxt = cur ^ 1, kn = k0 + 64;
      async_copy16(&Ks[nxt][tid * 8],        &Kp[(size_t)(kn + kk) * 768 + ch]);
      async_copy16(&Ks[nxt][2048 + tid * 8], &Kp[(size_t)(kn + kk) * 768 + 32 + ch]);
      async_copy16(&Vs[nxt][tid * 8],        &Vp[(size_t)kk * 2048 + kn + ch]);
      async_copy16(&Vs[nxt][2048 + tid * 8], &Vp[(size_t)kk * 2048 + kn + 32 + ch]);
    }

    // ---- QK^T swapped: s[kt][r] = P[q=c][k = kt*16 + g*4 + r] ----
    f32x4 s0[4] = {}, s1[4] = {};
#pragma unroll
    for (int kt = 0; kt < 4; ++kt) {
      bf16x8 kf0 = *(const bf16x8*)&Ks[cur][(kt * 16 + c) * 32 + g * 8];
      bf16x8 kf1 = *(const bf16x8*)&Ks[cur][2048 + (kt * 16 + c) * 32 + g * 8];
      s0[kt] = mfma16(kf0, qf0, s0[kt]);
      s0[kt] = mfma16(kf1, qf1, s0[kt]);
      s1[kt] = mfma16(kf0, qg0, s1[kt]);
      s1[kt] = mfma16(kf1, qg1, s1[kt]);
    }

    // ---- P = exp2(S): k-contiguous per lane -> one b64 write per (kt,sub) ----
#pragma unroll
    for (int kt = 0; kt < 4; ++kt) {
      float p0 = __builtin_amdgcn_exp2f(s0[kt][0]);
      float p1 = __builtin_amdgcn_exp2f(s0[kt][1]);
      float p2 = __builtin_amdgcn_exp2f(s0[kt][2]);
      float p3 = __builtin_amdgcn_exp2f(s0[kt][3]);
      lsum0 += (p0 + p1) + (p2 + p3);
      uint2 w; w.x = pk_bf16(p0, p1); w.y = pk_bf16(p2, p3);
      *(uint2*)&pw[c * 72 + kt * 16 + g * 4] = w;

      float r0 = __builtin_amdgcn_exp2f(s1[kt][0]);
      float r1 = __builtin_amdgcn_exp2f(s1[kt][1]);
      float r2 = __builtin_amdgcn_exp2f(s1[kt][2]);
      float r3 = __builtin_amdgcn_exp2f(s1[kt][3]);
      lsum1 += (r0 + r1) + (r2 + r3);
      uint2 w2; w2.x = pk_bf16(r0, r1); w2.y = pk_bf16(r2, r3);
      *(uint2*)&pw[(16 + c) * 72 + kt * 16 + g * 4] = w2;
    }
    __asm__ volatile("s_waitcnt lgkmcnt(0)" ::: "memory");

    // ---- PV: P A-frags (b128 pattern), V B-frags shared ----
#pragma unroll
    for (int kt2 = 0; kt2 < 2; ++kt2) {
      const bf16x8 pf0 = *(const bf16x8*)&pw[c * 72 + kt2 * 32 + g * 8];
      const bf16x8 pf1 = *(const bf16x8*)&pw[(16 + c) * 72 + kt2 * 32 + g * 8];
#pragma unroll
      for (int dt = 0; dt < 4; ++dt) {
        bf16x8 vf = *(const bf16x8*)&Vs[cur][kt2 * 2048 + (dt * 16 + c) * 32 + g * 8];
        o0[dt] = mfma16(pf0, vf, o0[dt]);
        o1[dt] = mfma16(pf1, vf, o1[dt]);
      }
    }
    cur ^= 1;
  }

  // row sums: lane (c,g) holds the g-slice of row q=c; reduce over g, then
  // broadcast to the C/D row layout (row = g*4 + r).
  float t0 = lsum0 + __shfl_xor(lsum0, 16);
  t0 += __shfl_xor(t0, 32);
  float t1 = lsum1 + __shfl_xor(lsum1, 16);
  t1 += __shfl_xor(t1, 32);
  float inv0 = 1.f / t0;
  float inv1 = 1.f / t1;
  float invr0[4], invr1[4];
#pragma unroll
  for (int r = 0; r < 4; ++r) {
    invr0[r] = __shfl(inv0, g * 4 + r);   // source lane q = g*4+r (lane < 16)
    invr1[r] = __shfl(inv1, g * 4 + r);
  }

#pragma unroll
  for (int dt = 0; dt < 4; ++dt)
#pragma unroll
    for (int r = 0; r < 4; ++r) {
      int n = q0 + g * 4 + r;
      out[(size_t)(b * 2048 + n) * 768 + h * 64 + dt * 16 + c] =
          f2bf(o0[dt][r] * invr0[r]);
      out[(size_t)(b * 2048 + n + 16) * 768 + h * 64 + dt * 16 + c] =
          f2bf(o1[dt][r] * invr1[r]);
    }
}

// ---------- launcher ----------
extern "C" void kernel_launch(void* const* d_in, const int* in_sizes, int n_in,
                              void* d_out, int out_size, void* d_ws, size_t ws_size,
                              hipStream_t stream) {
  const float* x      = (const float*)d_in[0];  // [4,2048,768] fp32
  const float* w_qkv  = (const float*)d_in[1];  // [2304,768]
  const float* w_proj = (const float*)d_in[2];  // [768,768]
  const float* b_proj = (const float*)d_in[3];  // [768]
  float* out = (float*)d_out;                   // [4,2048,768] fp32

  const int M = 8192;     // B*N
  const int C = 768;
  const int NQKV = 2304;

  // workspace layout (bf16 elements) — total ~33.8M u16 = 67.7 MB
  u16* xb     = (u16*)d_ws;                        // 8192*768
  u16* wqkvb  = xb + (size_t)M * C;                // 2304*768
  u16* wprojb = wqkvb + (size_t)NQKV * C;          // 768*768
  u16* Qb     = wprojb + (size_t)C * C;            // 8192*768
  u16* Kb     = Qb + (size_t)M * C;                // 8192*768
  u16* Vt     = Kb + (size_t)M * C;                // 4*12*64*2048
  u16* attn   = Vt + (size_t)M * C;                // 8192*768

  dim3 blk(256);
  // 0) convert all fp32 inputs to bf16 in one launch
  const int n0 = M * C, n1 = NQKV * C, n2 = C * C;
  cvt_all<<<dim3((n0 + n1 + n2) / 1024), blk, 0, stream>>>(
      x, xb, n0, w_qkv, wqkvb, n1, w_proj, wprojb, n2);

  // 1) qkv GEMM (128^2 tile, BK=32, dbuf — r10-best)
  gemm_qkv<<<dim3(NQKV / 128, M / 128), blk, 0, stream>>>(
      xb, wqkvb, Qb, Kb, Vt, M, NQKV, C);
  // 2) flash attention (v5 + XCD swizzle — r11-best)
  attn_flash<<<dim3(4 * 12 * 16), blk, 0, stream>>>(Qb, Kb, Vt, attn);
  // 3) out = attn @ w_proj^T + b  (128x64 tile, dbuf — r10-best)
  gemm_proj<<<dim3(C / 64, M / 128), blk, 0, stream>>>(
      attn, wprojb, b_proj, out, M, C, C);
}

// Round 13
// 216.952 us; speedup vs baseline: 1.0374x; 1.0330x over previous
//
#include <hip/hip_runtime.h>
#include <hip/hip_bf16.h>
#include <stdint.h>

#define DI __device__ __forceinline__

typedef __bf16 bf16x8 __attribute__((ext_vector_type(8)));
typedef float f32x4 __attribute__((ext_vector_type(4)));
typedef unsigned short u16;

// ---------- helpers ----------
DI u16 f2bf(float f) {
  union { float f; uint32_t u; } x; x.f = f;
  uint32_t r = (x.u + 0x7FFFu + ((x.u >> 16) & 1u)) >> 16;
  return (u16)r;
}
DI bf16x8 load16(const u16* p) { return *(const bf16x8*)p; }

DI void async_copy16(void* lds, const void* g) {
  __builtin_amdgcn_global_load_lds(
      (const __attribute__((address_space(1))) uint32_t*)g,
      (__attribute__((address_space(3))) uint32_t*)lds, 16, 0, 0);
}

DI f32x4 mfma16(bf16x8 a, bf16x8 b, f32x4 c) {
  return __builtin_amdgcn_mfma_f32_16x16x32_bf16(a, b, c, 0, 0, 0);
}

// pack 2 floats -> 2 bf16 (one v_cvt_pk_bf16_f32); low 16 bits = a
DI uint32_t pk_bf16(float a, float b) {
  union { __hip_bfloat162 v; uint32_t u; } r;
  r.v = __float22bfloat162_rn(make_float2(a, b));
  return r.u;
}

// scale * log2(e), folded into Q at GEMM1 epilogue
#define QSCALE (0.125f * 1.44269504088896340736f)

// ---------- fused fp32 -> bf16 conversion of all three inputs ----------
__global__ __launch_bounds__(256)
void cvt_all(const float* __restrict__ s0, u16* __restrict__ d0, int n0,
             const float* __restrict__ s1, u16* __restrict__ d1, int n1,
             const float* __restrict__ s2, u16* __restrict__ d2, int n2) {
  int i = (blockIdx.x * 256 + threadIdx.x) * 4;
  const float* s; u16* d;
  if (i < n0) { s = s0 + i; d = d0 + i; }
  else if (i < n0 + n1) { s = s1 + (i - n0); d = d1 + (i - n0); }
  else if (i < n0 + n1 + n2) { s = s2 + (i - n0 - n1); d = d2 + (i - n0 - n1); }
  else return;
  float4 v = *(const float4*)s;
  ushort4 o;
  o.x = f2bf(v.x); o.y = f2bf(v.y); o.z = f2bf(v.z); o.w = f2bf(v.w);
  *(ushort4*)d = o;
}

// ---------- QKV GEMM: 128^2 tile, BK=32, dbuf, ONE barrier/iter (r10-best) ----------
__global__ __launch_bounds__(256)
void gemm_qkv(const u16* __restrict__ A, const u16* __restrict__ Bm,
              u16* __restrict__ Qb, u16* __restrict__ Kb, u16* __restrict__ Vt,
              int M, int N, int K) {
  __shared__ u16 As[2][128 * 32];
  __shared__ u16 Bs[2][128 * 32];

  const int tid  = threadIdx.x;
  const int lane = tid & 63;
  const int wave = tid >> 6;
  // T1 XCD-aware swizzle: 1152 blocks = 8 xcd x 144
  const int lb  = blockIdx.x + 18 * blockIdx.y;
  const int swz = (lb & 7) * 144 + (lb >> 3);
  const int n0 = (swz % 18) * 128;
  const int m0 = (swz / 18) * 128;
  const int wm = (wave & 1) * 64;
  const int wn = (wave >> 1) * 64;
  const int c = lane & 15;
  const int g = lane >> 4;

  f32x4 acc[4][4] = {};

  // prologue: stage k0=0 into buf 0
#pragma unroll
  for (int i = 0; i < 2; ++i) {
    int j = i * 256 + tid;
    int row = j >> 2;
    int col = (j & 3) * 8;
    async_copy16(&As[0][j * 8], &A[(size_t)(m0 + row) * K + col]);
    async_copy16(&Bs[0][j * 8], &Bm[(size_t)(n0 + row) * K + col]);
  }

  int cur = 0;
  for (int k0 = 0; k0 < K; k0 += 32) {
    __syncthreads();                 // buf[cur] ready (staged an iter ago)

    if (k0 + 32 < K) {               // issue next-tile stage into other buffer
#pragma unroll
      for (int i = 0; i < 2; ++i) {
        int j = i * 256 + tid;
        int row = j >> 2;
        int col = (j & 3) * 8;
        async_copy16(&As[cur ^ 1][j * 8],
                     &A[(size_t)(m0 + row) * K + k0 + 32 + col]);
        async_copy16(&Bs[cur ^ 1][j * 8],
                     &Bm[(size_t)(n0 + row) * K + k0 + 32 + col]);
      }
    }

    bf16x8 af[4], bfr[4];
#pragma unroll
    for (int t = 0; t < 4; ++t) {
      af[t]  = *(const bf16x8*)&As[cur][(wm + t * 16 + c) * 32 + g * 8];
      bfr[t] = *(const bf16x8*)&Bs[cur][(wn + t * 16 + c) * 32 + g * 8];
    }
#pragma unroll
    for (int mt = 0; mt < 4; ++mt)
#pragma unroll
      for (int nt = 0; nt < 4; ++nt)
        acc[mt][nt] = mfma16(af[mt], bfr[nt], acc[mt][nt]);
    cur ^= 1;
  }

  if (n0 < 768) {            // Q, pre-scaled
#pragma unroll
    for (int nt = 0; nt < 4; ++nt) {
      int col = n0 + wn + nt * 16 + c;
#pragma unroll
      for (int mt = 0; mt < 4; ++mt)
#pragma unroll
        for (int r = 0; r < 4; ++r) {
          int row = m0 + wm + mt * 16 + g * 4 + r;
          Qb[(size_t)row * 768 + col] = f2bf(acc[mt][nt][r] * QSCALE);
        }
    }
  } else if (n0 < 1536) {    // K
#pragma unroll
    for (int nt = 0; nt < 4; ++nt) {
      int col = n0 - 768 + wn + nt * 16 + c;
#pragma unroll
      for (int mt = 0; mt < 4; ++mt)
#pragma unroll
        for (int r = 0; r < 4; ++r) {
          int row = m0 + wm + mt * 16 + g * 4 + r;
          Kb[(size_t)row * 768 + col] = f2bf(acc[mt][nt][r]);
        }
    }
  } else {                   // V transposed: Vt[((b*12+h)*64+d)*2048 + nseq]
#pragma unroll
    for (int nt = 0; nt < 4; ++nt) {
      int cv = n0 - 1536 + wn + nt * 16 + c;
      int hv = cv >> 6, d = cv & 63;
#pragma unroll
      for (int mt = 0; mt < 4; ++mt) {
        int row = m0 + wm + mt * 16 + g * 4;  // 4 consecutive rows
        int b = row >> 11, nn = row & 2047;
        ushort4 o;
        o.x = f2bf(acc[mt][nt][0]); o.y = f2bf(acc[mt][nt][1]);
        o.z = f2bf(acc[mt][nt][2]); o.w = f2bf(acc[mt][nt][3]);
        *(ushort4*)&Vt[(((size_t)b * 12 + hv) * 64 + d) * 2048 + nn] = o;
      }
    }
  }
}

// ---------- GEMM2: 128x64 tile (grid 768 = 3/CU), BK=32, dbuf (r10-best) ----------
__global__ __launch_bounds__(256)
void gemm_proj(const u16* __restrict__ A, const u16* __restrict__ Bm,
               const float* __restrict__ bias, float* __restrict__ Co,
               int M, int N, int K) {
  __shared__ u16 As[2][128 * 32];
  __shared__ u16 Bs[2][64 * 32];

  const int tid  = threadIdx.x;
  const int lane = tid & 63;
  const int wave = tid >> 6;
  // T1 XCD-aware swizzle: 768 blocks = 8 xcd x 96
  const int lb  = blockIdx.x + 12 * blockIdx.y;
  const int swz = (lb & 7) * 96 + (lb >> 3);
  const int n0 = (swz % 12) * 64;
  const int m0 = (swz / 12) * 128;
  const int wm = (wave & 1) * 64;
  const int wn = (wave >> 1) * 32;
  const int c = lane & 15;
  const int g = lane >> 4;

  f32x4 acc[4][2] = {};

#pragma unroll
  for (int i = 0; i < 2; ++i) {
    int j = i * 256 + tid;
    int row = j >> 2, col = (j & 3) * 8;
    async_copy16(&As[0][j * 8], &A[(size_t)(m0 + row) * K + col]);
  }
  {
    int row = tid >> 2, col = (tid & 3) * 8;
    async_copy16(&Bs[0][tid * 8], &Bm[(size_t)(n0 + row) * K + col]);
  }

  int cur = 0;
  for (int k0 = 0; k0 < K; k0 += 32) {
    __syncthreads();

    if (k0 + 32 < K) {
#pragma unroll
      for (int i = 0; i < 2; ++i) {
        int j = i * 256 + tid;
        int row = j >> 2, col = (j & 3) * 8;
        async_copy16(&As[cur ^ 1][j * 8],
                     &A[(size_t)(m0 + row) * K + k0 + 32 + col]);
      }
      {
        int row = tid >> 2, col = (tid & 3) * 8;
        async_copy16(&Bs[cur ^ 1][tid * 8],
                     &Bm[(size_t)(n0 + row) * K + k0 + 32 + col]);
      }
    }

    bf16x8 af[4], bfr[2];
#pragma unroll
    for (int t = 0; t < 4; ++t)
      af[t] = *(const bf16x8*)&As[cur][(wm + t * 16 + c) * 32 + g * 8];
#pragma unroll
    for (int t = 0; t < 2; ++t)
      bfr[t] = *(const bf16x8*)&Bs[cur][(wn + t * 16 + c) * 32 + g * 8];
#pragma unroll
    for (int mt = 0; mt < 4; ++mt)
#pragma unroll
      for (int nt = 0; nt < 2; ++nt)
        acc[mt][nt] = mfma16(af[mt], bfr[nt], acc[mt][nt]);
    cur ^= 1;
  }

#pragma unroll
  for (int nt = 0; nt < 2; ++nt) {
    int col = n0 + wn + nt * 16 + c;
    float bv = bias[col];
#pragma unroll
    for (int mt = 0; mt < 4; ++mt)
#pragma unroll
      for (int r = 0; r < 4; ++r) {
        int row = m0 + wm + mt * 16 + g * 4 + r;
        Co[(size_t)row * N + col] = acc[mt][nt][r] + bv;
      }
  }
}

// ---------- Flash attention v5 + XCD swizzle + T5 setprio (isolated A/B) ----------
// r11/r12 baseline 78.0-78.2 us. ONLY change: s_setprio(1) around the two
// MFMA clusters. Mechanism: 3 independent blocks/CU sit at different loop
// phases; priority keeps the matrix pipe fed while other waves run exp2/
// staging VALU (m191: +4-7% on independent-block attn; m190 GEMM-lockstep
// null). Datapath byte-identical to r12.
__global__ __launch_bounds__(256)
void attn_flash(const u16* __restrict__ Qb, const u16* __restrict__ Kb,
                const u16* __restrict__ Vt, u16* __restrict__ out) {
  __shared__ u16 Ks[2][2 * 64 * 32];
  __shared__ u16 Vs[2][2 * 64 * 32];
  __shared__ __align__(16) u16 Plds[4][32 * 72];  // 32q x 64k, stride 72

  const int tid  = threadIdx.x;
  const int lane = tid & 63;
  const int wave = tid >> 6;
  // T1 XCD swizzle: 768 blocks = 8 xcd x 96
  const int bid = blockIdx.x;
  const int swz = (bid & 7) * 96 + (bid >> 3);
  const int qchunk = swz & 15;        // N/128 = 16
  const int h = (swz >> 4) % 12;
  const int b = swz / 192;
  const int q0 = qchunk * 128 + wave * 32;
  const int c = lane & 15;
  const int g = lane >> 4;

  const u16* Qp = Qb + (size_t)b * 2048 * 768 + h * 64;   // row stride 768
  const u16* Kp = Kb + (size_t)b * 2048 * 768 + h * 64;
  const u16* Vp = Vt + ((size_t)b * 12 + h) * 64 * 2048;  // [d][nseq]

  u16* pw = &Plds[wave][0];

  // two q sub-tiles of 16 rows, two d-halves each (B-operand fragments)
  const bf16x8 qf0 = load16(&Qp[(size_t)(q0 + c) * 768 + g * 8]);
  const bf16x8 qf1 = load16(&Qp[(size_t)(q0 + c) * 768 + 32 + g * 8]);
  const bf16x8 qg0 = load16(&Qp[(size_t)(q0 + 16 + c) * 768 + g * 8]);
  const bf16x8 qg1 = load16(&Qp[(size_t)(q0 + 16 + c) * 768 + 32 + g * 8]);

  const int kk = tid >> 2;          // staged row 0..63
  const int ch = (tid & 3) * 8;     // u16 chunk offset within 32

  float lsum0 = 0.f, lsum1 = 0.f;
  f32x4 o0[4] = {}, o1[4] = {};

  // prologue: stage step 0 into buf 0
  async_copy16(&Ks[0][tid * 8],        &Kp[(size_t)kk * 768 + ch]);
  async_copy16(&Ks[0][2048 + tid * 8], &Kp[(size_t)kk * 768 + 32 + ch]);
  async_copy16(&Vs[0][tid * 8],        &Vp[(size_t)kk * 2048 + ch]);
  async_copy16(&Vs[0][2048 + tid * 8], &Vp[(size_t)kk * 2048 + 32 + ch]);

  int cur = 0;
  for (int k0 = 0; k0 < 2048; k0 += 64) {
    __syncthreads();  // drains this step's stage; protects buf^1 overwrite

    if (k0 + 64 < 2048) {             // stage next step into the other buffer
      int nxt = cur ^ 1, kn = k0 + 64;
      async_copy16(&Ks[nxt][tid * 8],        &Kp[(size_t)(kn + kk) * 768 + ch]);
      async_copy16(&Ks[nxt][2048 + tid * 8], &Kp[(size_t)(kn + kk) * 768 + 32 + ch]);
      async_copy16(&Vs[nxt][tid * 8],        &Vp[(size_t)kk * 2048 + kn + ch]);
      async_copy16(&Vs[nxt][2048 + tid * 8], &Vp[(size_t)kk * 2048 + kn + 32 + ch]);
    }

    // ---- QK^T swapped: s[kt][r] = P[q=c][k = kt*16 + g*4 + r] ----
    f32x4 s0[4] = {}, s1[4] = {};
    __builtin_amdgcn_s_setprio(1);
#pragma unroll
    for (int kt = 0; kt < 4; ++kt) {
      bf16x8 kf0 = *(const bf16x8*)&Ks[cur][(kt * 16 + c) * 32 + g * 8];
      bf16x8 kf1 = *(const bf16x8*)&Ks[cur][2048 + (kt * 16 + c) * 32 + g * 8];
      s0[kt] = mfma16(kf0, qf0, s0[kt]);
      s0[kt] = mfma16(kf1, qf1, s0[kt]);
      s1[kt] = mfma16(kf0, qg0, s1[kt]);
      s1[kt] = mfma16(kf1, qg1, s1[kt]);
    }
    __builtin_amdgcn_s_setprio(0);

    // ---- P = exp2(S): k-contiguous per lane -> one b64 write per (kt,sub) ----
#pragma unroll
    for (int kt = 0; kt < 4; ++kt) {
      float p0 = __builtin_amdgcn_exp2f(s0[kt][0]);
      float p1 = __builtin_amdgcn_exp2f(s0[kt][1]);
      float p2 = __builtin_amdgcn_exp2f(s0[kt][2]);
      float p3 = __builtin_amdgcn_exp2f(s0[kt][3]);
      lsum0 += (p0 + p1) + (p2 + p3);
      uint2 w; w.x = pk_bf16(p0, p1); w.y = pk_bf16(p2, p3);
      *(uint2*)&pw[c * 72 + kt * 16 + g * 4] = w;

      float r0 = __builtin_amdgcn_exp2f(s1[kt][0]);
      float r1 = __builtin_amdgcn_exp2f(s1[kt][1]);
      float r2 = __builtin_amdgcn_exp2f(s1[kt][2]);
      float r3 = __builtin_amdgcn_exp2f(s1[kt][3]);
      lsum1 += (r0 + r1) + (r2 + r3);
      uint2 w2; w2.x = pk_bf16(r0, r1); w2.y = pk_bf16(r2, r3);
      *(uint2*)&pw[(16 + c) * 72 + kt * 16 + g * 4] = w2;
    }
    __asm__ volatile("s_waitcnt lgkmcnt(0)" ::: "memory");

    // ---- PV: P A-frags (b128 pattern), V B-frags shared ----
    __builtin_amdgcn_s_setprio(1);
#pragma unroll
    for (int kt2 = 0; kt2 < 2; ++kt2) {
      const bf16x8 pf0 = *(const bf16x8*)&pw[c * 72 + kt2 * 32 + g * 8];
      const bf16x8 pf1 = *(const bf16x8*)&pw[(16 + c) * 72 + kt2 * 32 + g * 8];
#pragma unroll
      for (int dt = 0; dt < 4; ++dt) {
        bf16x8 vf = *(const bf16x8*)&Vs[cur][kt2 * 2048 + (dt * 16 + c) * 32 + g * 8];
        o0[dt] = mfma16(pf0, vf, o0[dt]);
        o1[dt] = mfma16(pf1, vf, o1[dt]);
      }
    }
    __builtin_amdgcn_s_setprio(0);
    cur ^= 1;
  }

  // row sums: lane (c,g) holds the g-slice of row q=c; reduce over g, then
  // broadcast to the C/D row layout (row = g*4 + r).
  float t0 = lsum0 + __shfl_xor(lsum0, 16);
  t0 += __shfl_xor(t0, 32);
  float t1 = lsum1 + __shfl_xor(lsum1, 16);
  t1 += __shfl_xor(t1, 32);
  float inv0 = 1.f / t0;
  float inv1 = 1.f / t1;
  float invr0[4], invr1[4];
#pragma unroll
  for (int r = 0; r < 4; ++r) {
    invr0[r] = __shfl(inv0, g * 4 + r);   // source lane q = g*4+r (lane < 16)
    invr1[r] = __shfl(inv1, g * 4 + r);
  }

#pragma unroll
  for (int dt = 0; dt < 4; ++dt)
#pragma unroll
    for (int r = 0; r < 4; ++r) {
      int n = q0 + g * 4 + r;
      out[(size_t)(b * 2048 + n) * 768 + h * 64 + dt * 16 + c] =
          f2bf(o0[dt][r] * invr0[r]);
      out[(size_t)(b * 2048 + n + 16) * 768 + h * 64 + dt * 16 + c] =
          f2bf(o1[dt][r] * invr1[r]);
    }
}

// ---------- launcher ----------
extern "C" void kernel_launch(void* const* d_in, const int* in_sizes, int n_in,
                              void* d_out, int out_size, void* d_ws, size_t ws_size,
                              hipStream_t stream) {
  const float* x      = (const float*)d_in[0];  // [4,2048,768] fp32
  const float* w_qkv  = (const float*)d_in[1];  // [2304,768]
  const float* w_proj = (const float*)d_in[2];  // [768,768]
  const float* b_proj = (const float*)d_in[3];  // [768]
  float* out = (float*)d_out;                   // [4,2048,768] fp32

  const int M = 8192;     // B*N
  const int C = 768;
  const int NQKV = 2304;

  // workspace layout (bf16 elements) — total ~33.8M u16 = 67.7 MB
  u16* xb     = (u16*)d_ws;                        // 8192*768
  u16* wqkvb  = xb + (size_t)M * C;                // 2304*768
  u16* wprojb = wqkvb + (size_t)NQKV * C;          // 768*768
  u16* Qb     = wprojb + (size_t)C * C;            // 8192*768
  u16* Kb     = Qb + (size_t)M * C;                // 8192*768
  u16* Vt     = Kb + (size_t)M * C;                // 4*12*64*2048
  u16* attn   = Vt + (size_t)M * C;                // 8192*768

  dim3 blk(256);
  // 0) convert all fp32 inputs to bf16 in one launch
  const int n0 = M * C, n1 = NQKV * C, n2 = C * C;
  cvt_all<<<dim3((n0 + n1 + n2) / 1024), blk, 0, stream>>>(
      x, xb, n0, w_qkv, wqkvb, n1, w_proj, wprojb, n2);

  // 1) qkv GEMM (128^2 tile, BK=32, dbuf — r10-best)
  gemm_qkv<<<dim3(NQKV / 128, M / 128), blk, 0, stream>>>(
      xb, wqkvb, Qb, Kb, Vt, M, NQKV, C);
  // 2) flash attention (v5 + XCD swizzle + setprio)
  attn_flash<<<dim3(4 * 12 * 16), blk, 0, stream>>>(Qb, Kb, Vt, attn);
  // 3) out = attn @ w_proj^T + b  (128x64 tile, dbuf — r10-best)
  gemm_proj<<<dim3(C / 64, M / 128), blk, 0, stream>>>(
      attn, wprojb, b_proj, out, M, C, C);
}

// Round 14
// 215.709 us; speedup vs baseline: 1.0434x; 1.0058x over previous
//
#include <hip/hip_runtime.h>
#include <hip/hip_bf16.h>
#include <stdint.h>

#define DI __device__ __forceinline__

typedef __bf16 bf16x8 __attribute__((ext_vector_type(8)));
typedef float f32x4 __attribute__((ext_vector_type(4)));
typedef unsigned short u16;

// ---------- helpers ----------
DI u16 f2bf(float f) {
  union { float f; uint32_t u; } x; x.f = f;
  uint32_t r = (x.u + 0x7FFFu + ((x.u >> 16) & 1u)) >> 16;
  return (u16)r;
}
DI bf16x8 load16(const u16* p) { return *(const bf16x8*)p; }

DI void async_copy16(void* lds, const void* g) {
  __builtin_amdgcn_global_load_lds(
      (const __attribute__((address_space(1))) uint32_t*)g,
      (__attribute__((address_space(3))) uint32_t*)lds, 16, 0, 0);
}

DI f32x4 mfma16(bf16x8 a, bf16x8 b, f32x4 c) {
  return __builtin_amdgcn_mfma_f32_16x16x32_bf16(a, b, c, 0, 0, 0);
}

// pack 2 floats -> 2 bf16 (one v_cvt_pk_bf16_f32); low 16 bits = a
DI uint32_t pk_bf16(float a, float b) {
  union { __hip_bfloat162 v; uint32_t u; } r;
  r.v = __float22bfloat162_rn(make_float2(a, b));
  return r.u;
}

// scale * log2(e), folded into Q at GEMM1 epilogue
#define QSCALE (0.125f * 1.44269504088896340736f)

// ---------- fused fp32 -> bf16 conversion of all three inputs ----------
__global__ __launch_bounds__(256)
void cvt_all(const float* __restrict__ s0, u16* __restrict__ d0, int n0,
             const float* __restrict__ s1, u16* __restrict__ d1, int n1,
             const float* __restrict__ s2, u16* __restrict__ d2, int n2) {
  int i = (blockIdx.x * 256 + threadIdx.x) * 4;
  const float* s; u16* d;
  if (i < n0) { s = s0 + i; d = d0 + i; }
  else if (i < n0 + n1) { s = s1 + (i - n0); d = d1 + (i - n0); }
  else if (i < n0 + n1 + n2) { s = s2 + (i - n0 - n1); d = d2 + (i - n0 - n1); }
  else return;
  float4 v = *(const float4*)s;
  ushort4 o;
  o.x = f2bf(v.x); o.y = f2bf(v.y); o.z = f2bf(v.z); o.w = f2bf(v.w);
  *(ushort4*)d = o;
}

// ---------- QKV GEMM: 128^2 tile, BK=32, TRIPLE-buffer, counted vmcnt (T4) ----------
// r10's dbuf drains vmcnt(0) at __syncthreads -> the just-issued prefetch gets
// only one compute phase (~<900cyc HBM latency) to land. Depth-2 pipeline:
// 3 buffers; iter t: {vmcnt(4) [retires stage t exactly; stage t+1's 4 loads
// stay in flight ACROSS the barrier], s_barrier, sched_barrier(0) [pins
// stage-issue after barrier: WAR vs iter t-1 readers of buf[(t+2)%3]],
// issue stage(t+2), compute buf[t%3]}. Each stage gets ~2 iters to land.
// Exactly 4 vmem ops/thread/iter -> counts exact. Tail: vmcnt(0) at last iter.
// LDS 3x16 = 48 KB.
__global__ __launch_bounds__(256)
void gemm_qkv(const u16* __restrict__ A, const u16* __restrict__ Bm,
              u16* __restrict__ Qb, u16* __restrict__ Kb, u16* __restrict__ Vt,
              int M, int N, int K) {
  __shared__ u16 As[3][128 * 32];
  __shared__ u16 Bs[3][128 * 32];

  const int tid  = threadIdx.x;
  const int lane = tid & 63;
  const int wave = tid >> 6;
  // T1 XCD-aware swizzle: 1152 blocks = 8 xcd x 144
  const int lb  = blockIdx.x + 18 * blockIdx.y;
  const int swz = (lb & 7) * 144 + (lb >> 3);
  const int n0 = (swz % 18) * 128;
  const int m0 = (swz / 18) * 128;
  const int wm = (wave & 1) * 64;
  const int wn = (wave >> 1) * 64;
  const int c = lane & 15;
  const int g = lane >> 4;

  const int srow = tid >> 2;            // staging row 0..63 (x2 chunks)
  const int scol = (tid & 3) * 8;

  f32x4 acc[4][4] = {};

  // prologue: stage k-tiles 0 and 1 into buf 0 and 1 (8 loads outstanding)
#pragma unroll
  for (int i = 0; i < 2; ++i) {
    int j = i * 256 + tid;
    int row = j >> 2;
    int col = (j & 3) * 8;
    async_copy16(&As[0][j * 8], &A[(size_t)(m0 + row) * K + col]);
    async_copy16(&Bs[0][j * 8], &Bm[(size_t)(n0 + row) * K + col]);
  }
#pragma unroll
  for (int i = 0; i < 2; ++i) {
    int j = i * 256 + tid;
    int row = j >> 2;
    int col = (j & 3) * 8;
    async_copy16(&As[1][j * 8], &A[(size_t)(m0 + row) * K + 32 + col]);
    async_copy16(&Bs[1][j * 8], &Bm[(size_t)(n0 + row) * K + 32 + col]);
  }

  int cur = 0;
  for (int k0 = 0; k0 < K; k0 += 32) {
    // counted wait: retire stage(t) only; stage(t+1) stays in flight
    if (k0 + 32 < K) {
      __asm__ volatile("s_waitcnt vmcnt(4)" ::: "memory");
    } else {
      __asm__ volatile("s_waitcnt vmcnt(0)" ::: "memory");
    }
    __builtin_amdgcn_s_barrier();
    __builtin_amdgcn_sched_barrier(0);   // nothing (esp. stage-issue) crosses up

    if (k0 + 64 < K) {                   // issue stage(t+2) into buf[(cur+2)%3]
      int s2 = cur + 2; if (s2 >= 3) s2 -= 3;
#pragma unroll
      for (int i = 0; i < 2; ++i) {
        int j = i * 256 + tid;
        int row = j >> 2;
        int col = (j & 3) * 8;
        async_copy16(&As[s2][j * 8],
                     &A[(size_t)(m0 + row) * K + k0 + 64 + col]);
        async_copy16(&Bs[s2][j * 8],
                     &Bm[(size_t)(n0 + row) * K + k0 + 64 + col]);
      }
    }

    bf16x8 af[4], bfr[4];
#pragma unroll
    for (int t = 0; t < 4; ++t) {
      af[t]  = *(const bf16x8*)&As[cur][(wm + t * 16 + c) * 32 + g * 8];
      bfr[t] = *(const bf16x8*)&Bs[cur][(wn + t * 16 + c) * 32 + g * 8];
    }
#pragma unroll
    for (int mt = 0; mt < 4; ++mt)
#pragma unroll
      for (int nt = 0; nt < 4; ++nt)
        acc[mt][nt] = mfma16(af[mt], bfr[nt], acc[mt][nt]);
    cur = (cur == 2) ? 0 : cur + 1;
  }

  if (n0 < 768) {            // Q, pre-scaled
#pragma unroll
    for (int nt = 0; nt < 4; ++nt) {
      int col = n0 + wn + nt * 16 + c;
#pragma unroll
      for (int mt = 0; mt < 4; ++mt)
#pragma unroll
        for (int r = 0; r < 4; ++r) {
          int row = m0 + wm + mt * 16 + g * 4 + r;
          Qb[(size_t)row * 768 + col] = f2bf(acc[mt][nt][r] * QSCALE);
        }
    }
  } else if (n0 < 1536) {    // K
#pragma unroll
    for (int nt = 0; nt < 4; ++nt) {
      int col = n0 - 768 + wn + nt * 16 + c;
#pragma unroll
      for (int mt = 0; mt < 4; ++mt)
#pragma unroll
        for (int r = 0; r < 4; ++r) {
          int row = m0 + wm + mt * 16 + g * 4 + r;
          Kb[(size_t)row * 768 + col] = f2bf(acc[mt][nt][r]);
        }
    }
  } else {                   // V transposed: Vt[((b*12+h)*64+d)*2048 + nseq]
#pragma unroll
    for (int nt = 0; nt < 4; ++nt) {
      int cv = n0 - 1536 + wn + nt * 16 + c;
      int hv = cv >> 6, d = cv & 63;
#pragma unroll
      for (int mt = 0; mt < 4; ++mt) {
        int row = m0 + wm + mt * 16 + g * 4;  // 4 consecutive rows
        int b = row >> 11, nn = row & 2047;
        ushort4 o;
        o.x = f2bf(acc[mt][nt][0]); o.y = f2bf(acc[mt][nt][1]);
        o.z = f2bf(acc[mt][nt][2]); o.w = f2bf(acc[mt][nt][3]);
        *(ushort4*)&Vt[(((size_t)b * 12 + hv) * 64 + d) * 2048 + nn] = o;
      }
    }
  }
}

// ---------- GEMM2: 128x64 tile (grid 768 = 3/CU), BK=32, dbuf (r10-best) ----------
__global__ __launch_bounds__(256)
void gemm_proj(const u16* __restrict__ A, const u16* __restrict__ Bm,
               const float* __restrict__ bias, float* __restrict__ Co,
               int M, int N, int K) {
  __shared__ u16 As[2][128 * 32];
  __shared__ u16 Bs[2][64 * 32];

  const int tid  = threadIdx.x;
  const int lane = tid & 63;
  const int wave = tid >> 6;
  // T1 XCD-aware swizzle: 768 blocks = 8 xcd x 96
  const int lb  = blockIdx.x + 12 * blockIdx.y;
  const int swz = (lb & 7) * 96 + (lb >> 3);
  const int n0 = (swz % 12) * 64;
  const int m0 = (swz / 12) * 128;
  const int wm = (wave & 1) * 64;
  const int wn = (wave >> 1) * 32;
  const int c = lane & 15;
  const int g = lane >> 4;

  f32x4 acc[4][2] = {};

#pragma unroll
  for (int i = 0; i < 2; ++i) {
    int j = i * 256 + tid;
    int row = j >> 2, col = (j & 3) * 8;
    async_copy16(&As[0][j * 8], &A[(size_t)(m0 + row) * K + col]);
  }
  {
    int row = tid >> 2, col = (tid & 3) * 8;
    async_copy16(&Bs[0][tid * 8], &Bm[(size_t)(n0 + row) * K + col]);
  }

  int cur = 0;
  for (int k0 = 0; k0 < K; k0 += 32) {
    __syncthreads();

    if (k0 + 32 < K) {
#pragma unroll
      for (int i = 0; i < 2; ++i) {
        int j = i * 256 + tid;
        int row = j >> 2, col = (j & 3) * 8;
        async_copy16(&As[cur ^ 1][j * 8],
                     &A[(size_t)(m0 + row) * K + k0 + 32 + col]);
      }
      {
        int row = tid >> 2, col = (tid & 3) * 8;
        async_copy16(&Bs[cur ^ 1][tid * 8],
                     &Bm[(size_t)(n0 + row) * K + k0 + 32 + col]);
      }
    }

    bf16x8 af[4], bfr[2];
#pragma unroll
    for (int t = 0; t < 4; ++t)
      af[t] = *(const bf16x8*)&As[cur][(wm + t * 16 + c) * 32 + g * 8];
#pragma unroll
    for (int t = 0; t < 2; ++t)
      bfr[t] = *(const bf16x8*)&Bs[cur][(wn + t * 16 + c) * 32 + g * 8];
#pragma unroll
    for (int mt = 0; mt < 4; ++mt)
#pragma unroll
      for (int nt = 0; nt < 2; ++nt)
        acc[mt][nt] = mfma16(af[mt], bfr[nt], acc[mt][nt]);
    cur ^= 1;
  }

#pragma unroll
  for (int nt = 0; nt < 2; ++nt) {
    int col = n0 + wn + nt * 16 + c;
    float bv = bias[col];
#pragma unroll
    for (int mt = 0; mt < 4; ++mt)
#pragma unroll
      for (int r = 0; r < 4; ++r) {
        int row = m0 + wm + mt * 16 + g * 4 + r;
        Co[(size_t)row * N + col] = acc[mt][nt][r] + bv;
      }
  }
}

// ---------- Flash attention v5 + XCD swizzle + setprio (r13, UNCHANGED) ----------
__global__ __launch_bounds__(256)
void attn_flash(const u16* __restrict__ Qb, const u16* __restrict__ Kb,
                const u16* __restrict__ Vt, u16* __restrict__ out) {
  __shared__ u16 Ks[2][2 * 64 * 32];
  __shared__ u16 Vs[2][2 * 64 * 32];
  __shared__ __align__(16) u16 Plds[4][32 * 72];  // 32q x 64k, stride 72

  const int tid  = threadIdx.x;
  const int lane = tid & 63;
  const int wave = tid >> 6;
  // T1 XCD swizzle: 768 blocks = 8 xcd x 96
  const int bid = blockIdx.x;
  const int swz = (bid & 7) * 96 + (bid >> 3);
  const int qchunk = swz & 15;        // N/128 = 16
  const int h = (swz >> 4) % 12;
  const int b = swz / 192;
  const int q0 = qchunk * 128 + wave * 32;
  const int c = lane & 15;
  const int g = lane >> 4;

  const u16* Qp = Qb + (size_t)b * 2048 * 768 + h * 64;   // row stride 768
  const u16* Kp = Kb + (size_t)b * 2048 * 768 + h * 64;
  const u16* Vp = Vt + ((size_t)b * 12 + h) * 64 * 2048;  // [d][nseq]

  u16* pw = &Plds[wave][0];

  // two q sub-tiles of 16 rows, two d-halves each (B-operand fragments)
  const bf16x8 qf0 = load16(&Qp[(size_t)(q0 + c) * 768 + g * 8]);
  const bf16x8 qf1 = load16(&Qp[(size_t)(q0 + c) * 768 + 32 + g * 8]);
  const bf16x8 qg0 = load16(&Qp[(size_t)(q0 + 16 + c) * 768 + g * 8]);
  const bf16x8 qg1 = load16(&Qp[(size_t)(q0 + 16 + c) * 768 + 32 + g * 8]);

  const int kk = tid >> 2;          // staged row 0..63
  const int ch = (tid & 3) * 8;     // u16 chunk offset within 32

  float lsum0 = 0.f, lsum1 = 0.f;
  f32x4 o0[4] = {}, o1[4] = {};

  // prologue: stage step 0 into buf 0
  async_copy16(&Ks[0][tid * 8],        &Kp[(size_t)kk * 768 + ch]);
  async_copy16(&Ks[0][2048 + tid * 8], &Kp[(size_t)kk * 768 + 32 + ch]);
  async_copy16(&Vs[0][tid * 8],        &Vp[(size_t)kk * 2048 + ch]);
  async_copy16(&Vs[0][2048 + tid * 8], &Vp[(size_t)kk * 2048 + 32 + ch]);

  int cur = 0;
  for (int k0 = 0; k0 < 2048; k0 += 64) {
    __syncthreads();  // drains this step's stage; protects buf^1 overwrite

    if (k0 + 64 < 2048) {             // stage next step into the other buffer
      int nxt = cur ^ 1, kn = k0 + 64;
      async_copy16(&Ks[nxt][tid * 8],        &Kp[(size_t)(kn + kk) * 768 + ch]);
      async_copy16(&Ks[nxt][2048 + tid * 8], &Kp[(size_t)(kn + kk) * 768 + 32 + ch]);
      async_copy16(&Vs[nxt][tid * 8],        &Vp[(size_t)kk * 2048 + kn + ch]);
      async_copy16(&Vs[nxt][2048 + tid * 8], &Vp[(size_t)kk * 2048 + kn + 32 + ch]);
    }

    // ---- QK^T swapped: s[kt][r] = P[q=c][k = kt*16 + g*4 + r] ----
    f32x4 s0[4] = {}, s1[4] = {};
    __builtin_amdgcn_s_setprio(1);
#pragma unroll
    for (int kt = 0; kt < 4; ++kt) {
      bf16x8 kf0 = *(const bf16x8*)&Ks[cur][(kt * 16 + c) * 32 + g * 8];
      bf16x8 kf1 = *(const bf16x8*)&Ks[cur][2048 + (kt * 16 + c) * 32 + g * 8];
      s0[kt] = mfma16(kf0, qf0, s0[kt]);
      s0[kt] = mfma16(kf1, qf1, s0[kt]);
      s1[kt] = mfma16(kf0, qg0, s1[kt]);
      s1[kt] = mfma16(kf1, qg1, s1[kt]);
    }
    __builtin_amdgcn_s_setprio(0);

    // ---- P = exp2(S): k-contiguous per lane -> one b64 write per (kt,sub) ----
#pragma unroll
    for (int kt = 0; kt < 4; ++kt) {
      float p0 = __builtin_amdgcn_exp2f(s0[kt][0]);
      float p1 = __builtin_amdgcn_exp2f(s0[kt][1]);
      float p2 = __builtin_amdgcn_exp2f(s0[kt][2]);
      float p3 = __builtin_amdgcn_exp2f(s0[kt][3]);
      lsum0 += (p0 + p1) + (p2 + p3);
      uint2 w; w.x = pk_bf16(p0, p1); w.y = pk_bf16(p2, p3);
      *(uint2*)&pw[c * 72 + kt * 16 + g * 4] = w;

      float r0 = __builtin_amdgcn_exp2f(s1[kt][0]);
      float r1 = __builtin_amdgcn_exp2f(s1[kt][1]);
      float r2 = __builtin_amdgcn_exp2f(s1[kt][2]);
      float r3 = __builtin_amdgcn_exp2f(s1[kt][3]);
      lsum1 += (r0 + r1) + (r2 + r3);
      uint2 w2; w2.x = pk_bf16(r0, r1); w2.y = pk_bf16(r2, r3);
      *(uint2*)&pw[(16 + c) * 72 + kt * 16 + g * 4] = w2;
    }
    __asm__ volatile("s_waitcnt lgkmcnt(0)" ::: "memory");

    // ---- PV: P A-frags (b128 pattern), V B-frags shared ----
    __builtin_amdgcn_s_setprio(1);
#pragma unroll
    for (int kt2 = 0; kt2 < 2; ++kt2) {
      const bf16x8 pf0 = *(const bf16x8*)&pw[c * 72 + kt2 * 32 + g * 8];
      const bf16x8 pf1 = *(const bf16x8*)&pw[(16 + c) * 72 + kt2 * 32 + g * 8];
#pragma unroll
      for (int dt = 0; dt < 4; ++dt) {
        bf16x8 vf = *(const bf16x8*)&Vs[cur][kt2 * 2048 + (dt * 16 + c) * 32 + g * 8];
        o0[dt] = mfma16(pf0, vf, o0[dt]);
        o1[dt] = mfma16(pf1, vf, o1[dt]);
      }
    }
    __builtin_amdgcn_s_setprio(0);
    cur ^= 1;
  }

  // row sums: lane (c,g) holds the g-slice of row q=c; reduce over g, then
  // broadcast to the C/D row layout (row = g*4 + r).
  float t0 = lsum0 + __shfl_xor(lsum0, 16);
  t0 += __shfl_xor(t0, 32);
  float t1 = lsum1 + __shfl_xor(lsum1, 16);
  t1 += __shfl_xor(t1, 32);
  float inv0 = 1.f / t0;
  float inv1 = 1.f / t1;
  float invr0[4], invr1[4];
#pragma unroll
  for (int r = 0; r < 4; ++r) {
    invr0[r] = __shfl(inv0, g * 4 + r);   // source lane q = g*4+r (lane < 16)
    invr1[r] = __shfl(inv1, g * 4 + r);
  }

#pragma unroll
  for (int dt = 0; dt < 4; ++dt)
#pragma unroll
    for (int r = 0; r < 4; ++r) {
      int n = q0 + g * 4 + r;
      out[(size_t)(b * 2048 + n) * 768 + h * 64 + dt * 16 + c] =
          f2bf(o0[dt][r] * invr0[r]);
      out[(size_t)(b * 2048 + n + 16) * 768 + h * 64 + dt * 16 + c] =
          f2bf(o1[dt][r] * invr1[r]);
    }
}

// ---------- launcher ----------
extern "C" void kernel_launch(void* const* d_in, const int* in_sizes, int n_in,
                              void* d_out, int out_size, void* d_ws, size_t ws_size,
                              hipStream_t stream) {
  const float* x      = (const float*)d_in[0];  // [4,2048,768] fp32
  const float* w_qkv  = (const float*)d_in[1];  // [2304,768]
  const float* w_proj = (const float*)d_in[2];  // [768,768]
  const float* b_proj = (const float*)d_in[3];  // [768]
  float* out = (float*)d_out;                   // [4,2048,768] fp32

  const int M = 8192;     // B*N
  const int C = 768;
  const int NQKV = 2304;

  // workspace layout (bf16 elements) — total ~33.8M u16 = 67.7 MB
  u16* xb     = (u16*)d_ws;                        // 8192*768
  u16* wqkvb  = xb + (size_t)M * C;                // 2304*768
  u16* wprojb = wqkvb + (size_t)NQKV * C;          // 768*768
  u16* Qb     = wprojb + (size_t)C * C;            // 8192*768
  u16* Kb     = Qb + (size_t)M * C;                // 8192*768
  u16* Vt     = Kb + (size_t)M * C;                // 4*12*64*2048
  u16* attn   = Vt + (size_t)M * C;                // 8192*768

  dim3 blk(256);
  // 0) convert all fp32 inputs to bf16 in one launch
  const int n0 = M * C, n1 = NQKV * C, n2 = C * C;
  cvt_all<<<dim3((n0 + n1 + n2) / 1024), blk, 0, stream>>>(
      x, xb, n0, w_qkv, wqkvb, n1, w_proj, wprojb, n2);

  // 1) qkv GEMM (128^2 tile, BK=32, triple-buffer + counted vmcnt)
  gemm_qkv<<<dim3(NQKV / 128, M / 128), blk, 0, stream>>>(
      xb, wqkvb, Qb, Kb, Vt, M, NQKV, C);
  // 2) flash attention (v5 + XCD swizzle + setprio — r13)
  attn_flash<<<dim3(4 * 12 * 16), blk, 0, stream>>>(Qb, Kb, Vt, attn);
  // 3) out = attn @ w_proj^T + b  (128x64 tile, dbuf — r10-best)
  gemm_proj<<<dim3(C / 64, M / 128), blk, 0, stream>>>(
      attn, wprojb, b_proj, out, M, C, C);
}